// Round 6
// baseline (6740.218 us; speedup 1.0000x reference)
//
#include <hip/hip_runtime.h>
#include <stdint.h>

// ---------------------------------------------------------------------------
// 3-layer packed-sequence LSTM, B=64 T=2048 D=40 H=164, FC->7. fp32 in/out.
//
// v7: force the register budget via LDS occupancy (the knob the backend
//     heuristic actually uses).
//
//     Evidence trail: v5 (launch_bounds 704,3) -> VGPR 84 (=512/6, 2 blk/CU).
//     v6 (launch_bounds 704,1) -> STILL 84: the AMDGPU backend targets the
//     occupancy implied by LDS (51.2KB -> 2 blocks/CU -> 6 waves/SIMD) and
//     caps VGPRs at 512/6=85; launch_bounds' 2nd arg is only a floor.
//     wB[24] (96 regs) therefore spills to scratch and is reloaded from L2
//     every timestep: 6600 cy/step observed vs ~900 cy issue model, with
//     scratch traffic invisible in FETCH_SIZE (L2-resident).
//
//     Fix: declare 86KB static LDS -> only ONE 704-thread block can ever
//     fit on a CU -> allocator budget = 512/ceil(11/4) = 170 VGPRs ->
//     rec body (~150 regs incl. wB) and gemm body (~145 regs incl. wf)
//     both register-resident. No algorithmic change.
//
//  Everything else byte-identical to v6 (passed, absmax 2^-10):
//  batch-major gx, bias folded into gx, staircase fusion, parity dbuf,
//  lgkm-only step barrier, hoisted ring-publish indices.
// ---------------------------------------------------------------------------

#define TT 2048
#define BB 64
#define GG 656   // 4*H (compact gate rows)
#define HH 164
#define EP 176   // padded elems per gate (16-aligned)
#define GP 704   // 4*EP padded gate rows
#define KPH 192  // K padded to 192 halves
#define KPD 96   // = KPH/2 dwords
#define CC 128   // chunk timesteps
#define NCH (TT/CC)   // 16
#define TSL 8    // timesteps per gemm slice block
#define NSL (CC/TSL)  // 16 slices
#define SMEMDW 21504  // 86KB static LDS: >80KB forces 1 block/CU -> 170-reg budget

typedef _Float16 half2v __attribute__((ext_vector_type(2)));
typedef _Float16 half8  __attribute__((ext_vector_type(8)));
typedef float    f32x4  __attribute__((ext_vector_type(4)));

// ---- workspace layout (bytes) ----
#define SZ_WIH   ((size_t)3*GG*KPH*2)          // f16 [3][656][192]
#define SZ_WHH   ((size_t)3*GP*KPH*2)          // f16 [3][704][192]
#define SZ_GX1   ((size_t)3*4*CC*GG*16*2)      // f16 [3][4][128][656][16] ~32.2MB
#define GX_SLOT_HALVES ((size_t)3*4*CC*GG*16)
#define SZ_HR    ((size_t)2*2*BB*CC*96*4)      // dw [2l][2slot][64][128][96]
#define SZ_SC    ((size_t)3*BB*HH*4)           // f32 c-state
#define SZ_SH    ((size_t)3*BB*96*4)           // dword h-state (f16 pairs)

__device__ __forceinline__ float sigmf(float x) { return 1.0f/(1.0f + __expf(-x)); }
__device__ __forceinline__ float tanhf_(float x) { return 2.0f/(1.0f + __expf(-2.0f*x)) - 1.0f; }

// ---------------------------------------------------------------------------
// weight prep: wih compact [3][656][192] (K zero-padded), whh padded
// [3][704][192] (rows g*176+e, zero for e>=164; K zero-padded)
// ---------------------------------------------------------------------------
__global__ void kprep_w(const float* wih0, const float* whh0,
                        const float* wih1, const float* whh1,
                        const float* wih2, const float* whh2,
                        _Float16* wih16, _Float16* whh16) {
  int i = threadIdx.x + blockIdx.x * blockDim.x;
  if (i >= 3*GP*KPH) return;
  int l = i / (GP*KPH);
  int r2 = i - l*(GP*KPH);
  int prow = r2 / KPH;
  int k = r2 - prow*KPH;
  const float* wihl = (l == 0) ? wih0 : ((l == 1) ? wih1 : wih2);
  const float* whhl = (l == 0) ? whh0 : ((l == 1) ? whh1 : whh2);
  int g = prow / EP, e = prow - g*EP;
  float vh = 0.f;
  if (e < HH && k < HH) vh = whhl[(size_t)(g*HH + e)*HH + k];
  whh16[((size_t)l*GP + prow)*KPH + k] = (_Float16)vh;
  if (prow < GG) {
    float vi = 0.f;
    if (l == 0) { if (k < 40) vi = wihl[(size_t)prow*40 + k]; }
    else        { if (k < HH) vi = wihl[(size_t)prow*HH + k]; }
    wih16[((size_t)l*GG + prow)*KPH + k] = (_Float16)vi;
  }
}

// ---------------------------------------------------------------------------
// batch-major input GEMM: one (l, bg, 8-t slice). 704 thr (11 waves).
// Per t: A=[16b x K] (LDS, row stride 100 dw), B=W_ih; D m=quad*4+r=batch,
// n=n15 -> gx[t][nt*16+n15][quad*4..+3] = one uint2 store. Bias folded in.
// ---------------------------------------------------------------------------
__device__ __forceinline__ void gemm_body(
    int l, int bg, int ts, int ch, const int* lengths, const float* x,
    const uint32_t* wihw, const uint32_t* hring, const float* bp,
    uint16_t* gxs, uint32_t* smem, int tid) {
  int maxlen = 1;
  #pragma unroll
  for (int bi = 0; bi < 16; ++bi) {
    int L = lengths[bg*16 + bi]; if (L < 1) L = 1; if (L > TT) L = TT;
    if (L > maxlen) maxlen = L;
  }
  const int tb = ts*TSL;                        // local t base within chunk
  const int t0 = ch*CC + tb;                    // absolute t base
  if (t0 >= maxlen) return;
  int tcnt = maxlen - t0; if (tcnt > TSL) tcnt = TSL;

  // ---- stage A: [TSL][16 batches][100 dw], full 96 dw (zeros pad K) ----
  if (l == 0) {
    for (int idx = tid; idx < TSL*16*96; idx += 704) {
      int tloc = idx / 1536, r = idx - tloc*1536, b = r / 96, dw = r - b*96;
      uint32_t v = 0;
      if (dw < 20) {
        const float* xs = x + ((size_t)(bg*16 + b)*TT + (t0 + tloc))*40 + dw*2;
        half2v pp; pp[0] = (_Float16)xs[0]; pp[1] = (_Float16)xs[1];
        v = __builtin_bit_cast(uint32_t, pp);
      }
      smem[(tloc*16 + b)*100 + dw] = v;
    }
  } else {
    const uint32_t* hbs = hring + ((size_t)((l-1)*2 + (ch & 1))*BB)*CC*96;
    for (int idx = tid; idx < TSL*16*96; idx += 704) {
      int tloc = idx / 1536, r = idx - tloc*1536, b = r / 96, dw = r - b*96;
      smem[(tloc*16 + b)*100 + dw] =
          hbs[((size_t)(bg*16 + b)*CC + tb + tloc)*96 + dw];
    }
  }
  __syncthreads();

  const int lane = tid & 63, wv = tid >> 6;
  const int quad = lane >> 4, n15 = lane & 15;
  uint16_t* gxo = gxs + ((size_t)(l*4 + bg)*CC + tb)*GG*16;

  // ---- hoisted W_ih fragments + bias (static indices; regs) ----
  half8 wf[4][6];
  float bv[4] = {0.f, 0.f, 0.f, 0.f};
  #pragma unroll
  for (int ni = 0; ni < 4; ++ni) {
    int nt = wv + ni*11;
    if (nt < 41) {
      int wrow = nt*16 + n15;
      const half8* bsrc = (const half8*)(wihw + ((size_t)l*GG + wrow)*KPD);
      #pragma unroll
      for (int kk = 0; kk < 6; ++kk) wf[ni][kk] = bsrc[kk*4 + quad];
      bv[ni] = bp[wrow];
    }
  }

  for (int tloc = 0; tloc < tcnt; ++tloc) {
    const half8* asrc = (const half8*)(smem + tloc*1600); // batch stride 25 h8
    half8 af[6];
    #pragma unroll
    for (int kk = 0; kk < 6; ++kk) af[kk] = asrc[n15*25 + kk*4 + quad];
    #pragma unroll
    for (int ni = 0; ni < 4; ++ni) {
      int nt = wv + ni*11;
      if (nt < 41) {
        int wrow = nt*16 + n15;
        f32x4 a0 = {0.f,0.f,0.f,0.f};
        #pragma unroll
        for (int kk = 0; kk < 6; ++kk)
          a0 = __builtin_amdgcn_mfma_f32_16x16x32_f16(af[kk], wf[ni][kk], a0, 0, 0, 0);
        half2v p0; p0[0] = (_Float16)(a0[0] + bv[ni]); p0[1] = (_Float16)(a0[1] + bv[ni]);
        half2v p1; p1[0] = (_Float16)(a0[2] + bv[ni]); p1[1] = (_Float16)(a0[3] + bv[ni]);
        uint2 pk;
        pk.x = __builtin_bit_cast(uint32_t, p0);
        pk.y = __builtin_bit_cast(uint32_t, p1);
        *(uint2*)(gxo + ((size_t)tloc*GG + wrow)*16 + quad*4) = pk;
      }
    }
  }
}

// ---------------------------------------------------------------------------
// MFMA recurrence body for one (l, batch-group of 16, chunk). 704 thr.
// wave wv owns elements e = 16wv..16wv+15; lane (n15,quad) holds all 4 gates
// of element e = 16wv+n15 for batches quad*4+r in acc[g][r].
// ---------------------------------------------------------------------------
__device__ __forceinline__ void rec_body(
    int l, int bg, int ch, const int* lengths,
    const uint32_t* whhw, const uint16_t* gxs, uint32_t* hring,
    float* state_c, uint32_t* state_h, uint32_t* smem, int tid) {

  int maxlen = 1;
  #pragma unroll
  for (int bi = 0; bi < 16; ++bi) {
    int L = lengths[bg*16 + bi]; if (L < 1) L = 1; if (L > TT) L = TT;
    if (L > maxlen) maxlen = L;
  }
  const int t0 = ch*CC;
  if (t0 >= maxlen) return;                     // group fully frozen
  int t1 = t0 + CC; if (t1 > maxlen) t1 = maxlen;

  const int wv = tid >> 6, ln = tid & 63;
  const int quad = ln >> 4, n15 = ln & 15;
  const int e = wv*16 + n15;                    // 0..175
  const int evalid = (e < HH);

  int lenv[4];
  #pragma unroll
  for (int r = 0; r < 4; ++r) {
    int L = lengths[bg*16 + quad*4 + r]; if (L < 1) L = 1; if (L > TT) L = TT;
    lenv[r] = L;
  }

  // resident W_hh fragments: 4 gates x 6 k-steps, half8 each (96 VGPRs)
  half8 wB[24];
  {
    const half8* wb8 = (const half8*)(whhw + (size_t)l*GP*KPD);
    #pragma unroll
    for (int g = 0; g < 4; ++g) {
      int row = g*EP + e;
      #pragma unroll
      for (int kk = 0; kk < 6; ++kk)
        wB[g*6 + kk] = wb8[(size_t)row*24 + kk*4 + quad];
    }
  }

  float creg[4] = {0.f, 0.f, 0.f, 0.f};
  if (ch > 0 && evalid) {
    #pragma unroll
    for (int r = 0; r < 4; ++r)
      creg[r] = state_c[((size_t)l*BB + bg*16 + quad*4 + r)*HH + e];
  }

  // h double buffer in LDS: [16 batches][100 dwords], halves 164..191 = 0
  uint32_t* hb0 = smem;
  uint32_t* hb1 = smem + 1600;
  for (int i2 = tid; i2 < 1600; i2 += 704) {
    int bb = i2 / 100, dd = i2 - bb*100;
    uint32_t v = 0;
    if (dd < 96 && ch > 0) v = state_h[((size_t)l*BB + bg*16 + bb)*96 + dd];
    hb0[i2] = v; hb1[i2] = v;
  }
  __syncthreads();

  // per-lane h bits for its 4 (batch, e) slots (re-published every step so
  // frozen sequences keep valid h in BOTH buffers)
  uint16_t hbits[4];
  #pragma unroll
  for (int r = 0; r < 4; ++r)
    hbits[r] = ((const uint16_t*)hb0)[(quad*4 + r)*200 + e];

  uint32_t* hrb = (l < 2)
      ? hring + ((size_t)(l*2 + (ch & 1))*BB)*CC*96 : (uint32_t*)0;
  const uint16_t* gxb = gxs + ((size_t)(l*4 + bg)*CC)*GG*16;
  uint32_t* shb = state_h + ((size_t)l*BB + bg*16)*96;

  // ring-publish slots (1536 dwords over 704 threads = 2..3 per thread),
  // indices hoisted out of the step loop (no per-step int division)
  const int rb0 = tid / 96,          rd0 = tid - rb0*96;
  const int i1s = tid + 704;
  const int rb1 = i1s / 96,          rd1 = i1s - rb1*96;
  const int i2s = tid + 1408;
  const int rb2 = i2s / 96,          rd2 = i2s - rb2*96;
  const int has2 = (i2s < 1536);
  const int lsrc0 = rb0*100 + rd0, lsrc1 = rb1*100 + rd1, lsrc2 = rb2*100 + rd2;
  uint32_t* hr0 = hrb ? hrb + ((size_t)(bg*16 + rb0)*CC)*96 + rd0 : (uint32_t*)0;
  uint32_t* hr1 = hrb ? hrb + ((size_t)(bg*16 + rb1)*CC)*96 + rd1 : (uint32_t*)0;
  uint32_t* hr2 = hrb ? hrb + ((size_t)(bg*16 + rb2)*CC)*96 + rd2 : (uint32_t*)0;

  uint2 gxp[4] = {};
  if (evalid) {
    #pragma unroll
    for (int g = 0; g < 4; ++g)
      gxp[g] = *(const uint2*)(gxb + ((size_t)g*HH + e)*16 + quad*4);
  }

  int p = 0;
  for (int t = t0; t < t1; ++t) {
    uint32_t* hin  = p ? hb1 : hb0;
    uint32_t* hout = p ? hb0 : hb1;

    // acc init = gx (bias already folded in by gemm)
    f32x4 acc[4];
    #pragma unroll
    for (int g = 0; g < 4; ++g) {
      const _Float16* gh = (const _Float16*)&gxp[g];
      #pragma unroll
      for (int r = 0; r < 4; ++r) acc[g][r] = (float)gh[r];
    }
    // prefetch next step's gx (hidden under MFMA + update)
    if (t + 1 < t1 && evalid) {
      int trow = t + 1 - t0;
      #pragma unroll
      for (int g = 0; g < 4; ++g)
        gxp[g] = *(const uint2*)(gxb + ((size_t)trow*GG + g*HH + e)*16 + quad*4);
    }
    // recurrent projection: [16x164] @ W_hh^T, 24 MFMA
    #pragma unroll
    for (int kk = 0; kk < 6; ++kk) {
      half8 af = *(const half8*)&hin[n15*100 + kk*16 + quad*4];
      acc[0] = __builtin_amdgcn_mfma_f32_16x16x32_f16(af, wB[kk],      acc[0], 0, 0, 0);
      acc[1] = __builtin_amdgcn_mfma_f32_16x16x32_f16(af, wB[6 + kk],  acc[1], 0, 0, 0);
      acc[2] = __builtin_amdgcn_mfma_f32_16x16x32_f16(af, wB[12 + kk], acc[2], 0, 0, 0);
      acc[3] = __builtin_amdgcn_mfma_f32_16x16x32_f16(af, wB[18 + kk], acc[3], 0, 0, 0);
    }
    // ring publish h(t-1) from hin
    if (hrb && t > t0) {
      int row96 = (t - 1 - t0)*96;
      hr0[row96] = hin[lsrc0];
      hr1[row96] = hin[lsrc1];
      if (has2) hr2[row96] = hin[lsrc2];
    }
    // cell update: lane has gates i,f,g,o of element e for 4 batches
    #pragma unroll
    for (int r = 0; r < 4; ++r) {
      float gi = acc[0][r], gf = acc[1][r], gg2 = acc[2][r], go = acc[3][r];
      float cn = sigmf(gf)*creg[r] + sigmf(gi)*tanhf_(gg2);
      float hv = sigmf(go)*tanhf_(cn);
      if (t < lenv[r]) {                        // per-batch freeze
        creg[r] = cn;
        _Float16 h16 = (_Float16)hv;
        hbits[r] = __builtin_bit_cast(uint16_t, h16);
      }
      if (evalid)
        ((uint16_t*)hout)[(quad*4 + r)*200 + e] = hbits[r];
    }
    // lgkm-only barrier: no vmcnt drain (ring stores / gx prefetch float).
    // All cross-wave data in this loop is LDS (hbuf), covered by lgkmcnt.
    asm volatile("s_waitcnt lgkmcnt(0)" ::: "memory");
    __builtin_amdgcn_s_barrier();
    p ^= 1;
  }

  // final ring publish + persist state
  uint32_t* hfin = p ? hb1 : hb0;
  {
    int rowl96 = (t1 - 1 - t0)*96;
    if (hrb) {
      hr0[rowl96] = hfin[lsrc0];
      hr1[rowl96] = hfin[lsrc1];
      if (has2) hr2[rowl96] = hfin[lsrc2];
    }
    shb[(size_t)rb0*96 + rd0] = hfin[lsrc0];
    shb[(size_t)rb1*96 + rd1] = hfin[lsrc1];
    if (has2) shb[(size_t)rb2*96 + rd2] = hfin[lsrc2];
  }
  if (evalid) {
    #pragma unroll
    for (int r = 0; r < 4; ++r)
      state_c[((size_t)l*BB + bg*16 + quad*4 + r)*HH + e] = creg[r];
  }
}

// ---------------------------------------------------------------------------
// fused step: blocks 0..191 = gemm(l, bg, tslice, ch=j-2l),
//             blocks 192..203 = rec(l, bg, ch=j-2l-1)
// gx double-buffered by chunk parity.
// 86KB static LDS: hard-limits residency to 1 block/CU, which is the only
// lever the backend's occupancy heuristic respects -> 170-VGPR budget ->
// wB/wf register-resident (v5/v6 were stuck at 84 regs = 2-block budget).
// ---------------------------------------------------------------------------
__global__ __launch_bounds__(704, 1) void kstep_f(
    int j, const int* lengths, const float* x,
    const uint32_t* wihw, const uint32_t* whhw,
    const float* b0, const float* b1, const float* b2,
    uint16_t* gx, uint32_t* hring, float* state_c, uint32_t* state_h) {
  __shared__ __align__(16) uint32_t smem[SMEMDW];       // 86 KB
  const int blk = blockIdx.x, tid = threadIdx.x;
  if (blk < 192) {
    const int l = blk >> 6, r = blk & 63, bg = r >> 4, ts = r & 15;
    const int ch = j - 2*l;
    if (ch < 0 || ch >= NCH) return;
    const float* bp = (l == 0) ? b0 : ((l == 1) ? b1 : b2);
    uint16_t* gxs = gx + (size_t)(ch & 1)*GX_SLOT_HALVES;
    gemm_body(l, bg, ts, ch, lengths, x, wihw, hring, bp, gxs, smem, tid);
  } else {
    const int idx = blk - 192;
    if (idx >= 12) return;
    const int l = idx >> 2, bg = idx & 3;
    const int ch = j - 2*l - 1;
    if (ch < 0 || ch >= NCH) return;
    const uint16_t* gxs = gx + (size_t)(ch & 1)*GX_SLOT_HALVES;
    rec_body(l, bg, ch, lengths, whhw, gxs, hring,
             state_c, state_h, smem, tid);
  }
}

// ---- sequential fallback (1 gx slot; gemm(i) then rec(i) each iteration) ----
__global__ __launch_bounds__(704, 1) void kgemm_s(
    int step, const int* lengths, const float* x,
    const uint32_t* wihw, const float* b0, const float* b1, const float* b2,
    uint16_t* gx, const uint32_t* hring) {
  __shared__ __align__(16) uint32_t smem[SMEMDW];
  const int blk = blockIdx.x;
  const int l = blk >> 6, r = blk & 63, bg = r >> 4, ts = r & 15;
  const int ch = step - l;
  if (ch < 0 || ch >= NCH) return;
  const float* bp = (l == 0) ? b0 : ((l == 1) ? b1 : b2);
  gemm_body(l, bg, ts, ch, lengths, x, wihw, hring, bp, gx, smem, threadIdx.x);
}

__global__ __launch_bounds__(704, 1) void krec_s(
    int step, const int* lengths,
    const uint32_t* whhw, const uint16_t* gx, uint32_t* hring,
    float* state_c, uint32_t* state_h) {
  __shared__ __align__(16) uint32_t smem[SMEMDW];
  const int idx = blockIdx.x;
  const int l = idx >> 2, bg = idx & 3;
  const int ch = step - l;
  if (ch < 0 || ch >= NCH) return;
  rec_body(l, bg, ch, lengths, whhw, gx, hring,
           state_c, state_h, smem, threadIdx.x);
}

// ---------------------------------------------------------------------------
// FC epilogue on layer-2 final hidden state
// ---------------------------------------------------------------------------
__global__ void kfc(const float* fcw, const float* fcb,
                    const uint32_t* state_h, float* out) {
  int b = blockIdx.x, o = threadIdx.x;
  if (o >= 7) return;
  const uint16_t* h16 = (const uint16_t*)(state_h + (size_t)(2*BB + b)*96);
  float s = fcb[o];
  for (int m = 0; m < HH; ++m) {
    _Float16 hv = __builtin_bit_cast(_Float16, h16[m]);
    s += fcw[o*HH + m] * (float)hv;
  }
  out[b*7 + o] = s;
}

// ---------------------------------------------------------------------------
extern "C" void kernel_launch(void* const* d_in, const int* in_sizes, int n_in,
                              void* d_out, int out_size, void* d_ws, size_t ws_size,
                              hipStream_t stream) {
  const float* x      = (const float*)d_in[0];
  const int*  lengths = (const int*)  d_in[1];
  const float* wih0   = (const float*)d_in[2];
  const float* whh0   = (const float*)d_in[3];
  const float* b0     = (const float*)d_in[4];
  const float* wih1   = (const float*)d_in[5];
  const float* whh1   = (const float*)d_in[6];
  const float* b1     = (const float*)d_in[7];
  const float* wih2   = (const float*)d_in[8];
  const float* whh2   = (const float*)d_in[9];
  const float* b2     = (const float*)d_in[10];
  const float* fcw    = (const float*)d_in[11];
  const float* fcb    = (const float*)d_in[12];

  const size_t off_wih = 0;
  const size_t off_whh = SZ_WIH;
  const size_t off_gx  = SZ_WIH + SZ_WHH;
  const size_t tail    = SZ_HR + SZ_SC + SZ_SH;
  const size_t need_fused = off_gx + 2*SZ_GX1 + tail;   // ~78.8 MB
  const size_t need_seq   = off_gx + 1*SZ_GX1 + tail;   // ~46.6 MB
  const int fused = (ws_size >= need_fused);
  if (!fused && ws_size < need_seq) return;             // loud, clean failure
  const size_t gx_bytes = fused ? 2*SZ_GX1 : SZ_GX1;
  const size_t off_hr = off_gx + gx_bytes;
  const size_t off_sc = off_hr + SZ_HR;
  const size_t off_sh = off_sc + SZ_SC;

  char* ws = (char*)d_ws;
  _Float16* wih16 = (_Float16*)(ws + off_wih);
  _Float16* whh16 = (_Float16*)(ws + off_whh);
  uint16_t* gxw   = (uint16_t*)(ws + off_gx);
  uint32_t* hrw   = (uint32_t*)(ws + off_hr);
  float*    scw   = (float*)   (ws + off_sc);
  uint32_t* shw   = (uint32_t*)(ws + off_sh);

  hipLaunchKernelGGL(kprep_w, dim3((3*GP*KPH + 255)/256), dim3(256), 0, stream,
                     wih0, whh0, wih1, whh1, wih2, whh2, wih16, whh16);

  if (fused) {
    for (int jj = 0; jj <= NCH + 4; ++jj) {             // j = 0..20
      hipLaunchKernelGGL(kstep_f, dim3(204), dim3(704), 0, stream,
                         jj, lengths, x, (const uint32_t*)wih16,
                         (const uint32_t*)whh16, b0, b1, b2,
                         gxw, hrw, scw, shw);
    }
  } else {
    for (int i = 0; i < NCH + 2; ++i) {
      hipLaunchKernelGGL(kgemm_s, dim3(192), dim3(704), 0, stream,
                         i, lengths, x, (const uint32_t*)wih16,
                         b0, b1, b2, gxw, (const uint32_t*)hrw);
      hipLaunchKernelGGL(krec_s, dim3(12), dim3(704), 0, stream,
                         i, lengths, (const uint32_t*)whh16,
                         (const uint16_t*)gxw, hrw, scw, shw);
    }
  }

  hipLaunchKernelGGL(kfc, dim3(64), dim3(64), 0, stream,
                     fcw, fcb, shw, (float*)d_out);
}

// Round 7
// 3996.313 us; speedup vs baseline: 1.6866x; 1.6866x over previous
//
#include <hip/hip_runtime.h>
#include <stdint.h>

// ---------------------------------------------------------------------------
// 3-layer packed-sequence LSTM, B=64 T=2048 D=40 H=164, FC->7. fp32 in/out.
//
// v8: VALU-issue diet for the MFMA recurrence.
//     Evidence: VGPR stuck at 84 across 3 occupancy knobs => wB is in AGPRs
//     (unified file, MFMA reads AGPR B natively), NOT spilled. Renormalized
//     VALUBusy on the 12 rec CUs ~72% => issue-bound. Biggest emitters:
//     (a) 20 correctly-rounded f32 divisions/lane/step in sigmoid/tanh
//         (~220 inst) -> replaced with v_rcp + v_exp (single-op each);
//     (b) address-taken gxp unpack (scratch risk) -> bit_cast extracts;
//     (c) ring publish via LDS round-trip -> direct u16 stores of hbits;
//     (d) full gx address recompute per step -> incrementing pointers.
//     Ring pad halves kept zero by one-time ring memset (NaN safety for
//     the next layer's staging MFMA with zero weight columns).
// ---------------------------------------------------------------------------

#define TT 2048
#define BB 64
#define GG 656   // 4*H (compact gate rows)
#define HH 164
#define EP 176   // padded elems per gate (16-aligned)
#define GP 704   // 4*EP padded gate rows
#define KPH 192  // K padded to 192 halves
#define KPD 96   // = KPH/2 dwords
#define CC 128   // chunk timesteps
#define NCH (TT/CC)   // 16
#define TSL 8    // timesteps per gemm slice block
#define NSL (CC/TSL)  // 16 slices

typedef _Float16 half2v __attribute__((ext_vector_type(2)));
typedef _Float16 half8  __attribute__((ext_vector_type(8)));
typedef float    f32x4  __attribute__((ext_vector_type(4)));

// ---- workspace layout (bytes) ----
#define SZ_WIH   ((size_t)3*GG*KPH*2)          // f16 [3][656][192]
#define SZ_WHH   ((size_t)3*GP*KPH*2)          // f16 [3][704][192]
#define SZ_GX1   ((size_t)3*4*CC*GG*16*2)      // f16 [3][4][128][656][16] ~32.2MB
#define GX_SLOT_HALVES ((size_t)3*4*CC*GG*16)
#define SZ_HR    ((size_t)2*2*BB*CC*96*4)      // dw [2l][2slot][64][128][96]
#define HR_DW    (2*2*BB*CC*96)                // ring dwords
#define SZ_SC    ((size_t)3*BB*HH*4)           // f32 c-state
#define SZ_SH    ((size_t)3*BB*96*4)           // dword h-state (f16 pairs)

#define LOG2E 1.4426950408889634f

__device__ __forceinline__ float fexp2(float x) {
#if __has_builtin(__builtin_amdgcn_exp2f)
  return __builtin_amdgcn_exp2f(x);
#else
  float r; asm("v_exp_f32 %0, %1" : "=v"(r) : "v"(x)); return r;
#endif
}
__device__ __forceinline__ float frcp(float x) {
#if __has_builtin(__builtin_amdgcn_rcpf)
  return __builtin_amdgcn_rcpf(x);
#else
  float r; asm("v_rcp_f32 %0, %1" : "=v"(r) : "v"(x)); return r;
#endif
}
// sigmoid via 2^x: 1/(1+2^(-x*log2e)); tanh(x) = 1 - 2/(1+2^(2x*log2e)).
// Edge cases saturate correctly (exp2->inf => rcp->0; exp2->0 => rcp(1)=1).
__device__ __forceinline__ float sigmf(float x) {
  return frcp(1.0f + fexp2(-LOG2E * x));
}
__device__ __forceinline__ float tanhf_(float x) {
  return __builtin_fmaf(-2.0f, frcp(1.0f + fexp2(2.0f * LOG2E * x)), 1.0f);
}

// ---------------------------------------------------------------------------
// weight prep: wih compact [3][656][192] (K zero-padded), whh padded
// [3][704][192] (rows g*176+e, zero for e>=164; K zero-padded)
// ---------------------------------------------------------------------------
__global__ void kprep_w(const float* wih0, const float* whh0,
                        const float* wih1, const float* whh1,
                        const float* wih2, const float* whh2,
                        _Float16* wih16, _Float16* whh16) {
  int i = threadIdx.x + blockIdx.x * blockDim.x;
  if (i >= 3*GP*KPH) return;
  int l = i / (GP*KPH);
  int r2 = i - l*(GP*KPH);
  int prow = r2 / KPH;
  int k = r2 - prow*KPH;
  const float* wihl = (l == 0) ? wih0 : ((l == 1) ? wih1 : wih2);
  const float* whhl = (l == 0) ? whh0 : ((l == 1) ? whh1 : whh2);
  int g = prow / EP, e = prow - g*EP;
  float vh = 0.f;
  if (e < HH && k < HH) vh = whhl[(size_t)(g*HH + e)*HH + k];
  whh16[((size_t)l*GP + prow)*KPH + k] = (_Float16)vh;
  if (prow < GG) {
    float vi = 0.f;
    if (l == 0) { if (k < 40) vi = wihl[(size_t)prow*40 + k]; }
    else        { if (k < HH) vi = wihl[(size_t)prow*HH + k]; }
    wih16[((size_t)l*GG + prow)*KPH + k] = (_Float16)vi;
  }
}

// one-time ring zero (pad halves must be 0 forever; rec only writes e<164)
__global__ void kzero(uint32_t* p, int n) {
  int i = threadIdx.x + blockIdx.x * blockDim.x;
  if (i < n) p[i] = 0u;
}

// ---------------------------------------------------------------------------
// batch-major input GEMM: one (l, bg, 8-t slice). 704 thr (11 waves).
// ---------------------------------------------------------------------------
__device__ __forceinline__ void gemm_body(
    int l, int bg, int ts, int ch, const int* lengths, const float* x,
    const uint32_t* wihw, const uint32_t* hring, const float* bp,
    uint16_t* gxs, uint32_t* smem, int tid) {
  int maxlen = 1;
  #pragma unroll
  for (int bi = 0; bi < 16; ++bi) {
    int L = lengths[bg*16 + bi]; if (L < 1) L = 1; if (L > TT) L = TT;
    if (L > maxlen) maxlen = L;
  }
  const int tb = ts*TSL;                        // local t base within chunk
  const int t0 = ch*CC + tb;                    // absolute t base
  if (t0 >= maxlen) return;
  int tcnt = maxlen - t0; if (tcnt > TSL) tcnt = TSL;

  // ---- stage A: [TSL][16 batches][100 dw], full 96 dw (zeros pad K) ----
  if (l == 0) {
    for (int idx = tid; idx < TSL*16*96; idx += 704) {
      int tloc = idx / 1536, r = idx - tloc*1536, b = r / 96, dw = r - b*96;
      uint32_t v = 0;
      if (dw < 20) {
        const float* xs = x + ((size_t)(bg*16 + b)*TT + (t0 + tloc))*40 + dw*2;
        half2v pp; pp[0] = (_Float16)xs[0]; pp[1] = (_Float16)xs[1];
        v = __builtin_bit_cast(uint32_t, pp);
      }
      smem[(tloc*16 + b)*100 + dw] = v;
    }
  } else {
    const uint32_t* hbs = hring + ((size_t)((l-1)*2 + (ch & 1))*BB)*CC*96;
    for (int idx = tid; idx < TSL*16*96; idx += 704) {
      int tloc = idx / 1536, r = idx - tloc*1536, b = r / 96, dw = r - b*96;
      smem[(tloc*16 + b)*100 + dw] =
          hbs[((size_t)(bg*16 + b)*CC + tb + tloc)*96 + dw];
    }
  }
  __syncthreads();

  const int lane = tid & 63, wv = tid >> 6;
  const int quad = lane >> 4, n15 = lane & 15;
  uint16_t* gxo = gxs + ((size_t)(l*4 + bg)*CC + tb)*GG*16;

  // ---- hoisted W_ih fragments + bias (static indices; regs) ----
  half8 wf[4][6];
  float bv[4] = {0.f, 0.f, 0.f, 0.f};
  #pragma unroll
  for (int ni = 0; ni < 4; ++ni) {
    int nt = wv + ni*11;
    if (nt < 41) {
      int wrow = nt*16 + n15;
      const half8* bsrc = (const half8*)(wihw + ((size_t)l*GG + wrow)*KPD);
      #pragma unroll
      for (int kk = 0; kk < 6; ++kk) wf[ni][kk] = bsrc[kk*4 + quad];
      bv[ni] = bp[wrow];
    }
  }

  for (int tloc = 0; tloc < tcnt; ++tloc) {
    const half8* asrc = (const half8*)(smem + tloc*1600); // batch stride 25 h8
    half8 af[6];
    #pragma unroll
    for (int kk = 0; kk < 6; ++kk) af[kk] = asrc[n15*25 + kk*4 + quad];
    #pragma unroll
    for (int ni = 0; ni < 4; ++ni) {
      int nt = wv + ni*11;
      if (nt < 41) {
        int wrow = nt*16 + n15;
        f32x4 a0 = {0.f,0.f,0.f,0.f};
        #pragma unroll
        for (int kk = 0; kk < 6; ++kk)
          a0 = __builtin_amdgcn_mfma_f32_16x16x32_f16(af[kk], wf[ni][kk], a0, 0, 0, 0);
        half2v p0; p0[0] = (_Float16)(a0[0] + bv[ni]); p0[1] = (_Float16)(a0[1] + bv[ni]);
        half2v p1; p1[0] = (_Float16)(a0[2] + bv[ni]); p1[1] = (_Float16)(a0[3] + bv[ni]);
        uint2 pk;
        pk.x = __builtin_bit_cast(uint32_t, p0);
        pk.y = __builtin_bit_cast(uint32_t, p1);
        *(uint2*)(gxo + ((size_t)tloc*GG + wrow)*16 + quad*4) = pk;
      }
    }
  }
}

// ---------------------------------------------------------------------------
// MFMA recurrence body for one (l, batch-group of 16, chunk). 704 thr.
// wave wv owns elements e = 16wv..16wv+15; lane (n15,quad) holds all 4 gates
// of element e = 16wv+n15 for batches quad*4+r in acc[g][r].
// ---------------------------------------------------------------------------
__device__ __forceinline__ void rec_body(
    int l, int bg, int ch, const int* lengths,
    const uint32_t* whhw, const uint16_t* gxs, uint32_t* hring,
    float* state_c, uint32_t* state_h, uint32_t* smem, int tid) {

  int maxlen = 1;
  #pragma unroll
  for (int bi = 0; bi < 16; ++bi) {
    int L = lengths[bg*16 + bi]; if (L < 1) L = 1; if (L > TT) L = TT;
    if (L > maxlen) maxlen = L;
  }
  const int t0 = ch*CC;
  if (t0 >= maxlen) return;                     // group fully frozen
  int t1 = t0 + CC; if (t1 > maxlen) t1 = maxlen;
  const int nst = t1 - t0;

  const int wv = tid >> 6, ln = tid & 63;
  const int quad = ln >> 4, n15 = ln & 15;
  const int e = wv*16 + n15;                    // 0..175
  const int evalid = (e < HH);

  int lenv[4];
  #pragma unroll
  for (int r = 0; r < 4; ++r) {
    int L = lengths[bg*16 + quad*4 + r]; if (L < 1) L = 1; if (L > TT) L = TT;
    lenv[r] = L;
  }

  // resident W_hh fragments: 4 gates x 6 k-steps, half8 each (96 regs/AGPRs)
  half8 wB[24];
  {
    const half8* wb8 = (const half8*)(whhw + (size_t)l*GP*KPD);
    #pragma unroll
    for (int g = 0; g < 4; ++g) {
      int row = g*EP + e;
      #pragma unroll
      for (int kk = 0; kk < 6; ++kk)
        wB[g*6 + kk] = wb8[(size_t)row*24 + kk*4 + quad];
    }
  }

  float creg[4] = {0.f, 0.f, 0.f, 0.f};
  if (ch > 0 && evalid) {
    #pragma unroll
    for (int r = 0; r < 4; ++r)
      creg[r] = state_c[((size_t)l*BB + bg*16 + quad*4 + r)*HH + e];
  }

  // h double buffer in LDS: [16 batches][100 dwords], halves 164..191 = 0
  uint32_t* hb0 = smem;
  uint32_t* hb1 = smem + 1600;
  for (int i2 = tid; i2 < 1600; i2 += 704) {
    int bb = i2 / 100, dd = i2 - bb*100;
    uint32_t v = 0;
    if (dd < 96 && ch > 0) v = state_h[((size_t)l*BB + bg*16 + bb)*96 + dd];
    hb0[i2] = v; hb1[i2] = v;
  }
  __syncthreads();

  // per-lane h bits for its 4 (batch, e) slots
  uint16_t hbits[4];
  #pragma unroll
  for (int r = 0; r < 4; ++r)
    hbits[r] = ((const uint16_t*)hb0)[(quad*4 + r)*200 + e];

  const uint16_t* gxb = gxs + ((size_t)(l*4 + bg)*CC)*GG*16;
  uint32_t* shb = state_h + ((size_t)l*BB + bg*16)*96;

  // incrementing gx prefetch pointers (one per gate), +GG*16 halves per t
  const uint16_t* gp[4];
  uint2 gxp[4];
  #pragma unroll
  for (int g = 0; g < 4; ++g) {
    gp[g] = gxb + ((size_t)g*HH + e)*16 + quad*4;
    gxp[g] = *(const uint2*)gp[g];
    gp[g] += GG*16;
  }

  // direct ring-publish pointers (u16, one per batch slot r), +192 halves/t
  const int dorb = (l < 2);
  uint16_t* rp[4];
  {
    uint16_t* hrb16 = (uint16_t*)(hring + ((size_t)(l*2 + (ch & 1))*BB)*CC*96);
    #pragma unroll
    for (int r = 0; r < 4; ++r)
      rp[r] = hrb16 + ((size_t)(bg*16 + quad*4 + r)*CC)*192 + e;
  }

  int p = 0;
  for (int it = 0; it < nst; ++it) {
    const int t = t0 + it;
    uint32_t* hin  = p ? hb1 : hb0;
    uint32_t* hout = p ? hb0 : hb1;

    // acc init = gx (bias folded by gemm); bit_cast extracts, no address-of
    f32x4 acc[4];
    #pragma unroll
    for (int g = 0; g < 4; ++g) {
      half2v lo = __builtin_bit_cast(half2v, gxp[g].x);
      half2v hi = __builtin_bit_cast(half2v, gxp[g].y);
      acc[g][0] = (float)lo[0]; acc[g][1] = (float)lo[1];
      acc[g][2] = (float)hi[0]; acc[g][3] = (float)hi[1];
    }
    // unconditional prefetch of next row (last iter reads in-bounds junk)
    #pragma unroll
    for (int g = 0; g < 4; ++g) {
      gxp[g] = *(const uint2*)gp[g];
      gp[g] += GG*16;
    }
    // recurrent projection: [16x164] @ W_hh^T, 24 MFMA
    #pragma unroll
    for (int kk = 0; kk < 6; ++kk) {
      half8 af = *(const half8*)&hin[n15*100 + kk*16 + quad*4];
      acc[0] = __builtin_amdgcn_mfma_f32_16x16x32_f16(af, wB[kk],      acc[0], 0, 0, 0);
      acc[1] = __builtin_amdgcn_mfma_f32_16x16x32_f16(af, wB[6 + kk],  acc[1], 0, 0, 0);
      acc[2] = __builtin_amdgcn_mfma_f32_16x16x32_f16(af, wB[12 + kk], acc[2], 0, 0, 0);
      acc[3] = __builtin_amdgcn_mfma_f32_16x16x32_f16(af, wB[18 + kk], acc[3], 0, 0, 0);
    }
    // cell update + LDS write + direct ring publish (all per-lane values)
    #pragma unroll
    for (int r = 0; r < 4; ++r) {
      float gi = acc[0][r], gf = acc[1][r], gg2 = acc[2][r], go = acc[3][r];
      float cn = sigmf(gf)*creg[r] + sigmf(gi)*tanhf_(gg2);
      float hv = sigmf(go)*tanhf_(cn);
      if (t < lenv[r]) {                        // per-batch freeze
        creg[r] = cn;
        _Float16 h16 = (_Float16)hv;
        hbits[r] = __builtin_bit_cast(uint16_t, h16);
      }
      if (evalid) {
        ((uint16_t*)hout)[(quad*4 + r)*200 + e] = hbits[r];
        if (dorb) *rp[r] = hbits[r];            // ring row it (h(t))
      }
      rp[r] += 192;
    }
    // lgkm-only barrier: no vmcnt drain (ring stores / gx prefetch float)
    asm volatile("s_waitcnt lgkmcnt(0)" ::: "memory");
    __builtin_amdgcn_s_barrier();
    p ^= 1;
  }

  // persist state (ring already fully published per-step)
  uint32_t* hfin = p ? hb1 : hb0;
  for (int i2 = tid; i2 < 1536; i2 += 704) {
    int bb = i2 / 96, dd = i2 - bb*96;
    shb[(size_t)bb*96 + dd] = hfin[bb*100 + dd];
  }
  if (evalid) {
    #pragma unroll
    for (int r = 0; r < 4; ++r)
      state_c[((size_t)l*BB + bg*16 + quad*4 + r)*HH + e] = creg[r];
  }
}

// ---------------------------------------------------------------------------
// fused step: blocks 0..191 = gemm(l, bg, tslice, ch=j-2l),
//             blocks 192..203 = rec(l, bg, ch=j-2l-1)
// ---------------------------------------------------------------------------
__global__ __launch_bounds__(704, 1) void kstep_f(
    int j, const int* lengths, const float* x,
    const uint32_t* wihw, const uint32_t* whhw,
    const float* b0, const float* b1, const float* b2,
    uint16_t* gx, uint32_t* hring, float* state_c, uint32_t* state_h) {
  __shared__ __align__(16) uint32_t smem[TSL*1600];     // 51.2 KB
  const int blk = blockIdx.x, tid = threadIdx.x;
  if (blk < 192) {
    const int l = blk >> 6, r = blk & 63, bg = r >> 4, ts = r & 15;
    const int ch = j - 2*l;
    if (ch < 0 || ch >= NCH) return;
    const float* bp = (l == 0) ? b0 : ((l == 1) ? b1 : b2);
    uint16_t* gxs = gx + (size_t)(ch & 1)*GX_SLOT_HALVES;
    gemm_body(l, bg, ts, ch, lengths, x, wihw, hring, bp, gxs, smem, tid);
  } else {
    const int idx = blk - 192;
    if (idx >= 12) return;
    const int l = idx >> 2, bg = idx & 3;
    const int ch = j - 2*l - 1;
    if (ch < 0 || ch >= NCH) return;
    const uint16_t* gxs = gx + (size_t)(ch & 1)*GX_SLOT_HALVES;
    rec_body(l, bg, ch, lengths, whhw, gxs, hring,
             state_c, state_h, smem, tid);
  }
}

// ---- sequential fallback (1 gx slot; gemm(i) then rec(i) each iteration) ----
__global__ __launch_bounds__(704, 1) void kgemm_s(
    int step, const int* lengths, const float* x,
    const uint32_t* wihw, const float* b0, const float* b1, const float* b2,
    uint16_t* gx, const uint32_t* hring) {
  __shared__ __align__(16) uint32_t smem[TSL*1600];
  const int blk = blockIdx.x;
  const int l = blk >> 6, r = blk & 63, bg = r >> 4, ts = r & 15;
  const int ch = step - l;
  if (ch < 0 || ch >= NCH) return;
  const float* bp = (l == 0) ? b0 : ((l == 1) ? b1 : b2);
  gemm_body(l, bg, ts, ch, lengths, x, wihw, hring, bp, gx, smem, threadIdx.x);
}

__global__ __launch_bounds__(704, 1) void krec_s(
    int step, const int* lengths,
    const uint32_t* whhw, const uint16_t* gx, uint32_t* hring,
    float* state_c, uint32_t* state_h) {
  __shared__ __align__(16) uint32_t smem[TSL*1600];
  const int idx = blockIdx.x;
  const int l = idx >> 2, bg = idx & 3;
  const int ch = step - l;
  if (ch < 0 || ch >= NCH) return;
  rec_body(l, bg, ch, lengths, whhw, gx, hring,
           state_c, state_h, smem, threadIdx.x);
}

// ---------------------------------------------------------------------------
// FC epilogue on layer-2 final hidden state
// ---------------------------------------------------------------------------
__global__ void kfc(const float* fcw, const float* fcb,
                    const uint32_t* state_h, float* out) {
  int b = blockIdx.x, o = threadIdx.x;
  if (o >= 7) return;
  const uint16_t* h16 = (const uint16_t*)(state_h + (size_t)(2*BB + b)*96);
  float s = fcb[o];
  for (int m = 0; m < HH; ++m) {
    _Float16 hv = __builtin_bit_cast(_Float16, h16[m]);
    s += fcw[o*HH + m] * (float)hv;
  }
  out[b*7 + o] = s;
}

// ---------------------------------------------------------------------------
extern "C" void kernel_launch(void* const* d_in, const int* in_sizes, int n_in,
                              void* d_out, int out_size, void* d_ws, size_t ws_size,
                              hipStream_t stream) {
  const float* x      = (const float*)d_in[0];
  const int*  lengths = (const int*)  d_in[1];
  const float* wih0   = (const float*)d_in[2];
  const float* whh0   = (const float*)d_in[3];
  const float* b0     = (const float*)d_in[4];
  const float* wih1   = (const float*)d_in[5];
  const float* whh1   = (const float*)d_in[6];
  const float* b1     = (const float*)d_in[7];
  const float* wih2   = (const float*)d_in[8];
  const float* whh2   = (const float*)d_in[9];
  const float* b2     = (const float*)d_in[10];
  const float* fcw    = (const float*)d_in[11];
  const float* fcb    = (const float*)d_in[12];

  const size_t off_wih = 0;
  const size_t off_whh = SZ_WIH;
  const size_t off_gx  = SZ_WIH + SZ_WHH;
  const size_t tail    = SZ_HR + SZ_SC + SZ_SH;
  const size_t need_fused = off_gx + 2*SZ_GX1 + tail;   // ~78.8 MB
  const size_t need_seq   = off_gx + 1*SZ_GX1 + tail;   // ~46.6 MB
  const int fused = (ws_size >= need_fused);
  if (!fused && ws_size < need_seq) return;             // loud, clean failure
  const size_t gx_bytes = fused ? 2*SZ_GX1 : SZ_GX1;
  const size_t off_hr = off_gx + gx_bytes;
  const size_t off_sc = off_hr + SZ_HR;
  const size_t off_sh = off_sc + SZ_SC;

  char* ws = (char*)d_ws;
  _Float16* wih16 = (_Float16*)(ws + off_wih);
  _Float16* whh16 = (_Float16*)(ws + off_whh);
  uint16_t* gxw   = (uint16_t*)(ws + off_gx);
  uint32_t* hrw   = (uint32_t*)(ws + off_hr);
  float*    scw   = (float*)   (ws + off_sc);
  uint32_t* shw   = (uint32_t*)(ws + off_sh);

  hipLaunchKernelGGL(kprep_w, dim3((3*GP*KPH + 255)/256), dim3(256), 0, stream,
                     wih0, whh0, wih1, whh1, wih2, whh2, wih16, whh16);
  hipLaunchKernelGGL(kzero, dim3((HR_DW + 255)/256), dim3(256), 0, stream,
                     hrw, HR_DW);

  if (fused) {
    for (int jj = 0; jj <= NCH + 4; ++jj) {             // j = 0..20
      hipLaunchKernelGGL(kstep_f, dim3(204), dim3(704), 0, stream,
                         jj, lengths, x, (const uint32_t*)wih16,
                         (const uint32_t*)whh16, b0, b1, b2,
                         gxw, hrw, scw, shw);
    }
  } else {
    for (int i = 0; i < NCH + 2; ++i) {
      hipLaunchKernelGGL(kgemm_s, dim3(192), dim3(704), 0, stream,
                         i, lengths, x, (const uint32_t*)wih16,
                         b0, b1, b2, gxw, (const uint32_t*)hrw);
      hipLaunchKernelGGL(krec_s, dim3(12), dim3(704), 0, stream,
                         i, lengths, (const uint32_t*)whh16,
                         (const uint16_t*)gxw, hrw, scw, shw);
    }
  }

  hipLaunchKernelGGL(kfc, dim3(64), dim3(64), 0, stream,
                     fcw, fcb, shw, (float*)d_out);
}

// Round 8
// 3461.084 us; speedup vs baseline: 1.9474x; 1.1546x over previous
//
#include <hip/hip_runtime.h>
#include <stdint.h>

// ---------------------------------------------------------------------------
// 3-layer packed-sequence LSTM, B=64 T=2048 D=40 H=164, FC->7. fp32 in/out.
//
// v9: spread the recurrence over 4x more CUs (12 -> 48 rec blocks).
//     Step cost model from v8 counters (3960 cy/step on 12 CUs):
//       VALU+trans ~1500 cy (scales with batches/block),
//       LDS reads  ~1050 cy (constant per block: 11 waves x 6KB A-frags),
//       MFMA        ~330 cy (constant per block).
//     Rec block now owns 4 batches with m-DUPLICATION: A rows 4q..4q+3 all
//     hold batch q's h, so D rows 4q..4q+3 are identical and each lane has
//     exactly ONE real cell-update slot (uniform; no exec-mask waste).
//     VALU per CU drops ~4x; LDS becomes the floor (~1050 cy/step).
//     48 rec + 192 gemm = 240 blocks <= 256 CUs.
//  Everything else identical to v8 (passed): fast rcp/exp2 activations,
//  batch-major gx, bias folded, staircase fusion, parity dbuf, lgkm-only
//  step barrier, direct ring publish, incrementing gx pointers.
// ---------------------------------------------------------------------------

#define TT 2048
#define BB 64
#define GG 656   // 4*H (compact gate rows)
#define HH 164
#define EP 176   // padded elems per gate (16-aligned)
#define GP 704   // 4*EP padded gate rows
#define KPH 192  // K padded to 192 halves
#define KPD 96   // = KPH/2 dwords
#define CC 128   // chunk timesteps
#define NCH (TT/CC)   // 16
#define TSL 8    // timesteps per gemm slice block
#define NSL (CC/TSL)  // 16 slices

typedef _Float16 half2v __attribute__((ext_vector_type(2)));
typedef _Float16 half8  __attribute__((ext_vector_type(8)));
typedef float    f32x4  __attribute__((ext_vector_type(4)));

// ---- workspace layout (bytes) ----
#define SZ_WIH   ((size_t)3*GG*KPH*2)          // f16 [3][656][192]
#define SZ_WHH   ((size_t)3*GP*KPH*2)          // f16 [3][704][192]
#define SZ_GX1   ((size_t)3*4*CC*GG*16*2)      // f16 [3][4][128][656][16] ~32.2MB
#define GX_SLOT_HALVES ((size_t)3*4*CC*GG*16)
#define SZ_HR    ((size_t)2*2*BB*CC*96*4)      // dw [2l][2slot][64][128][96]
#define HR_DW    (2*2*BB*CC*96)                // ring dwords
#define SZ_SC    ((size_t)3*BB*HH*4)           // f32 c-state
#define SZ_SH    ((size_t)3*BB*96*4)           // dword h-state (f16 pairs)

#define LOG2E 1.4426950408889634f

__device__ __forceinline__ float fexp2(float x) {
#if __has_builtin(__builtin_amdgcn_exp2f)
  return __builtin_amdgcn_exp2f(x);
#else
  float r; asm("v_exp_f32 %0, %1" : "=v"(r) : "v"(x)); return r;
#endif
}
__device__ __forceinline__ float frcp(float x) {
#if __has_builtin(__builtin_amdgcn_rcpf)
  return __builtin_amdgcn_rcpf(x);
#else
  float r; asm("v_rcp_f32 %0, %1" : "=v"(r) : "v"(x)); return r;
#endif
}
__device__ __forceinline__ float sigmf(float x) {
  return frcp(1.0f + fexp2(-LOG2E * x));
}
__device__ __forceinline__ float tanhf_(float x) {
  return __builtin_fmaf(-2.0f, frcp(1.0f + fexp2(2.0f * LOG2E * x)), 1.0f);
}

// ---------------------------------------------------------------------------
// weight prep: wih compact [3][656][192] (K zero-padded), whh padded
// [3][704][192] (rows g*176+e, zero for e>=164; K zero-padded)
// ---------------------------------------------------------------------------
__global__ void kprep_w(const float* wih0, const float* whh0,
                        const float* wih1, const float* whh1,
                        const float* wih2, const float* whh2,
                        _Float16* wih16, _Float16* whh16) {
  int i = threadIdx.x + blockIdx.x * blockDim.x;
  if (i >= 3*GP*KPH) return;
  int l = i / (GP*KPH);
  int r2 = i - l*(GP*KPH);
  int prow = r2 / KPH;
  int k = r2 - prow*KPH;
  const float* wihl = (l == 0) ? wih0 : ((l == 1) ? wih1 : wih2);
  const float* whhl = (l == 0) ? whh0 : ((l == 1) ? whh1 : whh2);
  int g = prow / EP, e = prow - g*EP;
  float vh = 0.f;
  if (e < HH && k < HH) vh = whhl[(size_t)(g*HH + e)*HH + k];
  whh16[((size_t)l*GP + prow)*KPH + k] = (_Float16)vh;
  if (prow < GG) {
    float vi = 0.f;
    if (l == 0) { if (k < 40) vi = wihl[(size_t)prow*40 + k]; }
    else        { if (k < HH) vi = wihl[(size_t)prow*HH + k]; }
    wih16[((size_t)l*GG + prow)*KPH + k] = (_Float16)vi;
  }
}

// one-time ring zero (pad halves must be 0 forever; rec only writes e<164)
__global__ void kzero(uint32_t* p, int n) {
  int i = threadIdx.x + blockIdx.x * blockDim.x;
  if (i < n) p[i] = 0u;
}

// ---------------------------------------------------------------------------
// batch-major input GEMM: one (l, bg4 of 16 batches, 8-t slice). 704 thr.
// ---------------------------------------------------------------------------
__device__ __forceinline__ void gemm_body(
    int l, int bg, int ts, int ch, const int* lengths, const float* x,
    const uint32_t* wihw, const uint32_t* hring, const float* bp,
    uint16_t* gxs, uint32_t* smem, int tid) {
  int maxlen = 1;
  #pragma unroll
  for (int bi = 0; bi < 16; ++bi) {
    int L = lengths[bg*16 + bi]; if (L < 1) L = 1; if (L > TT) L = TT;
    if (L > maxlen) maxlen = L;
  }
  const int tb = ts*TSL;                        // local t base within chunk
  const int t0 = ch*CC + tb;                    // absolute t base
  if (t0 >= maxlen) return;
  int tcnt = maxlen - t0; if (tcnt > TSL) tcnt = TSL;

  // ---- stage A: [TSL][16 batches][100 dw], full 96 dw (zeros pad K) ----
  if (l == 0) {
    for (int idx = tid; idx < TSL*16*96; idx += 704) {
      int tloc = idx / 1536, r = idx - tloc*1536, b = r / 96, dw = r - b*96;
      uint32_t v = 0;
      if (dw < 20) {
        const float* xs = x + ((size_t)(bg*16 + b)*TT + (t0 + tloc))*40 + dw*2;
        half2v pp; pp[0] = (_Float16)xs[0]; pp[1] = (_Float16)xs[1];
        v = __builtin_bit_cast(uint32_t, pp);
      }
      smem[(tloc*16 + b)*100 + dw] = v;
    }
  } else {
    const uint32_t* hbs = hring + ((size_t)((l-1)*2 + (ch & 1))*BB)*CC*96;
    for (int idx = tid; idx < TSL*16*96; idx += 704) {
      int tloc = idx / 1536, r = idx - tloc*1536, b = r / 96, dw = r - b*96;
      smem[(tloc*16 + b)*100 + dw] =
          hbs[((size_t)(bg*16 + b)*CC + tb + tloc)*96 + dw];
    }
  }
  __syncthreads();

  const int lane = tid & 63, wv = tid >> 6;
  const int quad = lane >> 4, n15 = lane & 15;
  uint16_t* gxo = gxs + ((size_t)(l*4 + bg)*CC + tb)*GG*16;

  // ---- hoisted W_ih fragments + bias (static indices; regs) ----
  half8 wf[4][6];
  float bv[4] = {0.f, 0.f, 0.f, 0.f};
  #pragma unroll
  for (int ni = 0; ni < 4; ++ni) {
    int nt = wv + ni*11;
    if (nt < 41) {
      int wrow = nt*16 + n15;
      const half8* bsrc = (const half8*)(wihw + ((size_t)l*GG + wrow)*KPD);
      #pragma unroll
      for (int kk = 0; kk < 6; ++kk) wf[ni][kk] = bsrc[kk*4 + quad];
      bv[ni] = bp[wrow];
    }
  }

  for (int tloc = 0; tloc < tcnt; ++tloc) {
    const half8* asrc = (const half8*)(smem + tloc*1600); // batch stride 25 h8
    half8 af[6];
    #pragma unroll
    for (int kk = 0; kk < 6; ++kk) af[kk] = asrc[n15*25 + kk*4 + quad];
    #pragma unroll
    for (int ni = 0; ni < 4; ++ni) {
      int nt = wv + ni*11;
      if (nt < 41) {
        int wrow = nt*16 + n15;
        f32x4 a0 = {0.f,0.f,0.f,0.f};
        #pragma unroll
        for (int kk = 0; kk < 6; ++kk)
          a0 = __builtin_amdgcn_mfma_f32_16x16x32_f16(af[kk], wf[ni][kk], a0, 0, 0, 0);
        half2v p0; p0[0] = (_Float16)(a0[0] + bv[ni]); p0[1] = (_Float16)(a0[1] + bv[ni]);
        half2v p1; p1[0] = (_Float16)(a0[2] + bv[ni]); p1[1] = (_Float16)(a0[3] + bv[ni]);
        uint2 pk;
        pk.x = __builtin_bit_cast(uint32_t, p0);
        pk.y = __builtin_bit_cast(uint32_t, p1);
        *(uint2*)(gxo + ((size_t)tloc*GG + wrow)*16 + quad*4) = pk;
      }
    }
  }
}

// ---------------------------------------------------------------------------
// MFMA recurrence for one (l, 4-batch group, chunk). 704 thr (11 waves).
// m-duplication: LDS A rows 4q..4q+3 all hold batch (bg*4+q)'s h, so lane
// (n15, quad) computes all 4 gates of element e = wv*16+n15 for exactly ONE
// batch gb = bg*4+quad in acc[g][0] (rows 1..3 are discarded duplicates).
// ---------------------------------------------------------------------------
__device__ __forceinline__ void rec_body(
    int l, int bg, int ch, const int* lengths,
    const uint32_t* whhw, const uint16_t* gxs, uint32_t* hring,
    float* state_c, uint32_t* state_h, uint32_t* smem, int tid) {

  const int gb0 = bg*4;
  int maxlen = 1;
  #pragma unroll
  for (int bi = 0; bi < 4; ++bi) {
    int L = lengths[gb0 + bi]; if (L < 1) L = 1; if (L > TT) L = TT;
    if (L > maxlen) maxlen = L;
  }
  const int t0 = ch*CC;
  if (t0 >= maxlen) return;                     // group fully frozen
  int t1 = t0 + CC; if (t1 > maxlen) t1 = maxlen;
  const int nst = t1 - t0;

  const int wv = tid >> 6, ln = tid & 63;
  const int quad = ln >> 4, n15 = ln & 15;
  const int e = wv*16 + n15;                    // 0..175
  const int evalid = (e < HH);
  const int gb = gb0 + quad;                    // this lane's batch

  int lenq = lengths[gb]; if (lenq < 1) lenq = 1; if (lenq > TT) lenq = TT;

  // resident W_hh fragments: 4 gates x 6 k-steps, half8 each (96 regs/AGPRs)
  half8 wB[24];
  {
    const half8* wb8 = (const half8*)(whhw + (size_t)l*GP*KPD);
    #pragma unroll
    for (int g = 0; g < 4; ++g) {
      int row = g*EP + e;
      #pragma unroll
      for (int kk = 0; kk < 6; ++kk)
        wB[g*6 + kk] = wb8[(size_t)row*24 + kk*4 + quad];
    }
  }

  float creg = 0.f;
  if (ch > 0 && evalid)
    creg = state_c[((size_t)l*BB + gb)*HH + e];

  // h double buffer in LDS: rows m=0..15, row m = batch gb0+(m>>2), dup x4
  uint32_t* hb0 = smem;
  uint32_t* hb1 = smem + 1600;
  for (int i2 = tid; i2 < 1600; i2 += 704) {
    int bb = i2 / 100, dd = i2 - bb*100;
    uint32_t v = 0;
    if (dd < 96 && ch > 0) v = state_h[((size_t)l*BB + gb0 + (bb >> 2))*96 + dd];
    hb0[i2] = v; hb1[i2] = v;
  }
  __syncthreads();

  // per-lane h bits for its (batch gb, element e)
  uint16_t hbit = ((const uint16_t*)hb0)[(quad*4)*200 + e];

  const uint16_t* gxb = gxs + ((size_t)(l*4 + (bg >> 2))*CC)*GG*16;
  const int boff = (bg & 3)*4 + quad;           // batch index within 16-group

  // incrementing gx pointers (u16 per gate), +GG*16 halves per t
  const uint16_t* gp[4];
  uint16_t gxv[4];
  #pragma unroll
  for (int g = 0; g < 4; ++g) {
    gp[g] = gxb + ((size_t)g*HH + e)*16 + boff;
    gxv[g] = *gp[g];
    gp[g] += GG*16;
  }

  // direct ring-publish pointer (u16), +192 halves per t
  const int dorb = (l < 2);
  uint16_t* rp;
  {
    uint16_t* hrb16 = (uint16_t*)(hring + ((size_t)(l*2 + (ch & 1))*BB)*CC*96);
    rp = hrb16 + ((size_t)gb*CC)*192 + e;
  }

  int p = 0;
  for (int it = 0; it < nst; ++it) {
    const int t = t0 + it;
    uint32_t* hin  = p ? hb1 : hb0;
    uint32_t* hout = p ? hb0 : hb1;

    // acc init = gx broadcast (rows duplicate the same batch)
    f32x4 acc[4];
    #pragma unroll
    for (int g = 0; g < 4; ++g) {
      float v = (float)__builtin_bit_cast(_Float16, gxv[g]);
      acc[g][0] = v; acc[g][1] = v; acc[g][2] = v; acc[g][3] = v;
    }
    // unconditional prefetch of next row (last iter reads in-bounds junk)
    #pragma unroll
    for (int g = 0; g < 4; ++g) {
      gxv[g] = *gp[g];
      gp[g] += GG*16;
    }
    // recurrent projection: [16(dup) x 164] @ W_hh^T, 24 MFMA
    #pragma unroll
    for (int kk = 0; kk < 6; ++kk) {
      half8 af = *(const half8*)&hin[n15*100 + kk*16 + quad*4];
      acc[0] = __builtin_amdgcn_mfma_f32_16x16x32_f16(af, wB[kk],      acc[0], 0, 0, 0);
      acc[1] = __builtin_amdgcn_mfma_f32_16x16x32_f16(af, wB[6 + kk],  acc[1], 0, 0, 0);
      acc[2] = __builtin_amdgcn_mfma_f32_16x16x32_f16(af, wB[12 + kk], acc[2], 0, 0, 0);
      acc[3] = __builtin_amdgcn_mfma_f32_16x16x32_f16(af, wB[18 + kk], acc[3], 0, 0, 0);
    }
    // cell update: ONE slot per lane (row 0 of this lane's quad-block)
    {
      float gi = acc[0][0], gf = acc[1][0], gg2 = acc[2][0], go = acc[3][0];
      float cn = sigmf(gf)*creg + sigmf(gi)*tanhf_(gg2);
      float hv = sigmf(go)*tanhf_(cn);
      if (t < lenq) {                           // per-batch freeze
        creg = cn;
        _Float16 h16 = (_Float16)hv;
        hbit = __builtin_bit_cast(uint16_t, h16);
      }
      if (evalid) {
        uint16_t* ho = (uint16_t*)hout;
        ho[(quad*4 + 0)*200 + e] = hbit;        // duplicate into all 4 rows
        ho[(quad*4 + 1)*200 + e] = hbit;
        ho[(quad*4 + 2)*200 + e] = hbit;
        ho[(quad*4 + 3)*200 + e] = hbit;
        if (dorb) *rp = hbit;                   // ring row it = h(t)
      }
      rp += 192;
    }
    // lgkm-only barrier: no vmcnt drain (ring stores / gx prefetch float)
    asm volatile("s_waitcnt lgkmcnt(0)" ::: "memory");
    __builtin_amdgcn_s_barrier();
    p ^= 1;
  }

  // persist state (ring already fully published per-step)
  uint32_t* hfin = p ? hb1 : hb0;
  uint32_t* shb = state_h + ((size_t)l*BB + gb0)*96;
  for (int i2 = tid; i2 < 4*96; i2 += 704) {
    int bb = i2 / 96, dd = i2 - bb*96;
    shb[(size_t)bb*96 + dd] = hfin[(bb*4)*100 + dd];
  }
  if (evalid)
    state_c[((size_t)l*BB + gb)*HH + e] = creg;
}

// ---------------------------------------------------------------------------
// fused step: blocks 0..191 = gemm(l, bg4, tslice, ch=j-2l),
//             blocks 192..239 = rec(l, bg of 4 batches, ch=j-2l-1)
// ---------------------------------------------------------------------------
__global__ __launch_bounds__(704, 1) void kstep_f(
    int j, const int* lengths, const float* x,
    const uint32_t* wihw, const uint32_t* whhw,
    const float* b0, const float* b1, const float* b2,
    uint16_t* gx, uint32_t* hring, float* state_c, uint32_t* state_h) {
  __shared__ __align__(16) uint32_t smem[TSL*1600];     // 51.2 KB
  const int blk = blockIdx.x, tid = threadIdx.x;
  if (blk < 192) {
    const int l = blk >> 6, r = blk & 63, bg = r >> 4, ts = r & 15;
    const int ch = j - 2*l;
    if (ch < 0 || ch >= NCH) return;
    const float* bp = (l == 0) ? b0 : ((l == 1) ? b1 : b2);
    uint16_t* gxs = gx + (size_t)(ch & 1)*GX_SLOT_HALVES;
    gemm_body(l, bg, ts, ch, lengths, x, wihw, hring, bp, gxs, smem, tid);
  } else {
    const int idx = blk - 192;
    if (idx >= 48) return;
    const int l = idx >> 4, bg = idx & 15;
    const int ch = j - 2*l - 1;
    if (ch < 0 || ch >= NCH) return;
    const uint16_t* gxs = gx + (size_t)(ch & 1)*GX_SLOT_HALVES;
    rec_body(l, bg, ch, lengths, whhw, gxs, hring,
             state_c, state_h, smem, tid);
  }
}

// ---- sequential fallback (1 gx slot; gemm(i) then rec(i) each iteration) ----
__global__ __launch_bounds__(704, 1) void kgemm_s(
    int step, const int* lengths, const float* x,
    const uint32_t* wihw, const float* b0, const float* b1, const float* b2,
    uint16_t* gx, const uint32_t* hring) {
  __shared__ __align__(16) uint32_t smem[TSL*1600];
  const int blk = blockIdx.x;
  const int l = blk >> 6, r = blk & 63, bg = r >> 4, ts = r & 15;
  const int ch = step - l;
  if (ch < 0 || ch >= NCH) return;
  const float* bp = (l == 0) ? b0 : ((l == 1) ? b1 : b2);
  gemm_body(l, bg, ts, ch, lengths, x, wihw, hring, bp, gx, smem, threadIdx.x);
}

__global__ __launch_bounds__(704, 1) void krec_s(
    int step, const int* lengths,
    const uint32_t* whhw, const uint16_t* gx, uint32_t* hring,
    float* state_c, uint32_t* state_h) {
  __shared__ __align__(16) uint32_t smem[TSL*1600];
  const int idx = blockIdx.x;
  const int l = idx >> 4, bg = idx & 15;
  const int ch = step - l;
  if (ch < 0 || ch >= NCH) return;
  rec_body(l, bg, ch, lengths, whhw, gx, hring,
           state_c, state_h, smem, threadIdx.x);
}

// ---------------------------------------------------------------------------
// FC epilogue on layer-2 final hidden state
// ---------------------------------------------------------------------------
__global__ void kfc(const float* fcw, const float* fcb,
                    const uint32_t* state_h, float* out) {
  int b = blockIdx.x, o = threadIdx.x;
  if (o >= 7) return;
  const uint16_t* h16 = (const uint16_t*)(state_h + (size_t)(2*BB + b)*96);
  float s = fcb[o];
  for (int m = 0; m < HH; ++m) {
    _Float16 hv = __builtin_bit_cast(_Float16, h16[m]);
    s += fcw[o*HH + m] * (float)hv;
  }
  out[b*7 + o] = s;
}

// ---------------------------------------------------------------------------
extern "C" void kernel_launch(void* const* d_in, const int* in_sizes, int n_in,
                              void* d_out, int out_size, void* d_ws, size_t ws_size,
                              hipStream_t stream) {
  const float* x      = (const float*)d_in[0];
  const int*  lengths = (const int*)  d_in[1];
  const float* wih0   = (const float*)d_in[2];
  const float* whh0   = (const float*)d_in[3];
  const float* b0     = (const float*)d_in[4];
  const float* wih1   = (const float*)d_in[5];
  const float* whh1   = (const float*)d_in[6];
  const float* b1     = (const float*)d_in[7];
  const float* wih2   = (const float*)d_in[8];
  const float* whh2   = (const float*)d_in[9];
  const float* b2     = (const float*)d_in[10];
  const float* fcw    = (const float*)d_in[11];
  const float* fcb    = (const float*)d_in[12];

  const size_t off_wih = 0;
  const size_t off_whh = SZ_WIH;
  const size_t off_gx  = SZ_WIH + SZ_WHH;
  const size_t tail    = SZ_HR + SZ_SC + SZ_SH;
  const size_t need_fused = off_gx + 2*SZ_GX1 + tail;   // ~78.8 MB
  const size_t need_seq   = off_gx + 1*SZ_GX1 + tail;   // ~46.6 MB
  const int fused = (ws_size >= need_fused);
  if (!fused && ws_size < need_seq) return;             // loud, clean failure
  const size_t gx_bytes = fused ? 2*SZ_GX1 : SZ_GX1;
  const size_t off_hr = off_gx + gx_bytes;
  const size_t off_sc = off_hr + SZ_HR;
  const size_t off_sh = off_sc + SZ_SC;

  char* ws = (char*)d_ws;
  _Float16* wih16 = (_Float16*)(ws + off_wih);
  _Float16* whh16 = (_Float16*)(ws + off_whh);
  uint16_t* gxw   = (uint16_t*)(ws + off_gx);
  uint32_t* hrw   = (uint32_t*)(ws + off_hr);
  float*    scw   = (float*)   (ws + off_sc);
  uint32_t* shw   = (uint32_t*)(ws + off_sh);

  hipLaunchKernelGGL(kprep_w, dim3((3*GP*KPH + 255)/256), dim3(256), 0, stream,
                     wih0, whh0, wih1, whh1, wih2, whh2, wih16, whh16);
  hipLaunchKernelGGL(kzero, dim3((HR_DW + 255)/256), dim3(256), 0, stream,
                     hrw, HR_DW);

  if (fused) {
    for (int jj = 0; jj <= NCH + 4; ++jj) {             // j = 0..20
      hipLaunchKernelGGL(kstep_f, dim3(240), dim3(704), 0, stream,
                         jj, lengths, x, (const uint32_t*)wih16,
                         (const uint32_t*)whh16, b0, b1, b2,
                         gxw, hrw, scw, shw);
    }
  } else {
    for (int i = 0; i < NCH + 2; ++i) {
      hipLaunchKernelGGL(kgemm_s, dim3(192), dim3(704), 0, stream,
                         i, lengths, x, (const uint32_t*)wih16,
                         b0, b1, b2, gxw, (const uint32_t*)hrw);
      hipLaunchKernelGGL(krec_s, dim3(48), dim3(704), 0, stream,
                         i, lengths, (const uint32_t*)whh16,
                         (const uint16_t*)gxw, hrw, scw, shw);
    }
  }

  hipLaunchKernelGGL(kfc, dim3(64), dim3(64), 0, stream,
                     fcw, fcb, shw, (float*)d_out);
}

// Round 9
// 2314.098 us; speedup vs baseline: 2.9127x; 1.4957x over previous
//
#include <hip/hip_runtime.h>
#include <stdint.h>

// ---------------------------------------------------------------------------
// 3-layer packed-sequence LSTM, B=64 T=2048 D=40 H=164, FC->7. fp32 in/out.
//
// v10: v9 shape (48 rec blocks x 4 batches, m-duplication) with the measured
//      overheads removed. v9 per-SIMD step model (matches 3320 cy observed):
//      MFMA 66x16cy=1060 + VALU ~1200 + LDS ~500. This round:
//   * gx layout [l][bg4][t][656][4]: writer (gemm uint2 store) already
//     4-batch granular; rec wave reads contiguous 128B/gate -> kills the
//     4x XCD line amplification (FETCH 73MB -> ~30MB) and collapses the 4
//     incrementing 64-bit gx pointers into ONE pointer + const offsets.
//   * acc has no splat-init: first MFMA per gate takes C=0, gx is added
//     after the chain to the single used slot (saves 16 movs/step).
//   * single hout ds_write: D row m depends only on A row m, so the 3
//     duplicate A rows feed discarded D rows -> stale junk is harmless.
//   * hoisted LDS lane offsets out of the step loop.
//  Unchanged from v9 (passed): staircase fusion, parity dbuf, lgkm-only
//  step barrier, fast rcp/exp2 activations, direct ring publish.
// ---------------------------------------------------------------------------

#define TT 2048
#define BB 64
#define GG 656   // 4*H (compact gate rows)
#define HH 164
#define EP 176   // padded elems per gate (16-aligned)
#define GP 704   // 4*EP padded gate rows
#define KPH 192  // K padded to 192 halves
#define KPD 96   // = KPH/2 dwords
#define CC 128   // chunk timesteps
#define NCH (TT/CC)   // 16
#define TSL 8    // timesteps per gemm slice block
#define NSL (CC/TSL)  // 16 slices

typedef _Float16 half2v __attribute__((ext_vector_type(2)));
typedef _Float16 half8  __attribute__((ext_vector_type(8)));
typedef float    f32x4  __attribute__((ext_vector_type(4)));

// ---- workspace layout (bytes) ----
#define SZ_WIH   ((size_t)3*GG*KPH*2)          // f16 [3][656][192]
#define SZ_WHH   ((size_t)3*GP*KPH*2)          // f16 [3][704][192]
#define SZ_GX1   ((size_t)3*16*CC*GG*4*2)      // f16 [3][16 bg4][128][656][4] ~32.2MB
#define GX_SLOT_HALVES ((size_t)3*16*CC*GG*4)
#define SZ_HR    ((size_t)2*2*BB*CC*96*4)      // dw [2l][2slot][64][128][96]
#define HR_DW    (2*2*BB*CC*96)                // ring dwords
#define SZ_SC    ((size_t)3*BB*HH*4)           // f32 c-state
#define SZ_SH    ((size_t)3*BB*96*4)           // dword h-state (f16 pairs)

#define LOG2E 1.4426950408889634f

__device__ __forceinline__ float fexp2(float x) {
#if __has_builtin(__builtin_amdgcn_exp2f)
  return __builtin_amdgcn_exp2f(x);
#else
  float r; asm("v_exp_f32 %0, %1" : "=v"(r) : "v"(x)); return r;
#endif
}
__device__ __forceinline__ float frcp(float x) {
#if __has_builtin(__builtin_amdgcn_rcpf)
  return __builtin_amdgcn_rcpf(x);
#else
  float r; asm("v_rcp_f32 %0, %1" : "=v"(r) : "v"(x)); return r;
#endif
}
__device__ __forceinline__ float sigmf(float x) {
  return frcp(1.0f + fexp2(-LOG2E * x));
}
__device__ __forceinline__ float tanhf_(float x) {
  return __builtin_fmaf(-2.0f, frcp(1.0f + fexp2(2.0f * LOG2E * x)), 1.0f);
}

// ---------------------------------------------------------------------------
// weight prep: wih compact [3][656][192] (K zero-padded), whh padded
// [3][704][192] (rows g*176+e, zero for e>=164; K zero-padded)
// ---------------------------------------------------------------------------
__global__ void kprep_w(const float* wih0, const float* whh0,
                        const float* wih1, const float* whh1,
                        const float* wih2, const float* whh2,
                        _Float16* wih16, _Float16* whh16) {
  int i = threadIdx.x + blockIdx.x * blockDim.x;
  if (i >= 3*GP*KPH) return;
  int l = i / (GP*KPH);
  int r2 = i - l*(GP*KPH);
  int prow = r2 / KPH;
  int k = r2 - prow*KPH;
  const float* wihl = (l == 0) ? wih0 : ((l == 1) ? wih1 : wih2);
  const float* whhl = (l == 0) ? whh0 : ((l == 1) ? whh1 : whh2);
  int g = prow / EP, e = prow - g*EP;
  float vh = 0.f;
  if (e < HH && k < HH) vh = whhl[(size_t)(g*HH + e)*HH + k];
  whh16[((size_t)l*GP + prow)*KPH + k] = (_Float16)vh;
  if (prow < GG) {
    float vi = 0.f;
    if (l == 0) { if (k < 40) vi = wihl[(size_t)prow*40 + k]; }
    else        { if (k < HH) vi = wihl[(size_t)prow*HH + k]; }
    wih16[((size_t)l*GG + prow)*KPH + k] = (_Float16)vi;
  }
}

// one-time ring zero (pad halves must be 0 forever; rec only writes e<164)
__global__ void kzero(uint32_t* p, int n) {
  int i = threadIdx.x + blockIdx.x * blockDim.x;
  if (i < n) p[i] = 0u;
}

// ---------------------------------------------------------------------------
// batch-major input GEMM: one (l, 16-batch group, 8-t slice). 704 thr.
// D m=quad*4+r=batch, n=n15 -> lane stores batches quad*4..+3 of row wrow as
// ONE uint2 into gx slab (l*16 + bg*4 + quad).
// ---------------------------------------------------------------------------
__device__ __forceinline__ void gemm_body(
    int l, int bg, int ts, int ch, const int* lengths, const float* x,
    const uint32_t* wihw, const uint32_t* hring, const float* bp,
    uint16_t* gxs, uint32_t* smem, int tid) {
  int maxlen = 1;
  #pragma unroll
  for (int bi = 0; bi < 16; ++bi) {
    int L = lengths[bg*16 + bi]; if (L < 1) L = 1; if (L > TT) L = TT;
    if (L > maxlen) maxlen = L;
  }
  const int tb = ts*TSL;                        // local t base within chunk
  const int t0 = ch*CC + tb;                    // absolute t base
  if (t0 >= maxlen) return;
  int tcnt = maxlen - t0; if (tcnt > TSL) tcnt = TSL;

  // ---- stage A: [TSL][16 batches][100 dw], full 96 dw (zeros pad K) ----
  if (l == 0) {
    for (int idx = tid; idx < TSL*16*96; idx += 704) {
      int tloc = idx / 1536, r = idx - tloc*1536, b = r / 96, dw = r - b*96;
      uint32_t v = 0;
      if (dw < 20) {
        const float* xs = x + ((size_t)(bg*16 + b)*TT + (t0 + tloc))*40 + dw*2;
        half2v pp; pp[0] = (_Float16)xs[0]; pp[1] = (_Float16)xs[1];
        v = __builtin_bit_cast(uint32_t, pp);
      }
      smem[(tloc*16 + b)*100 + dw] = v;
    }
  } else {
    const uint32_t* hbs = hring + ((size_t)((l-1)*2 + (ch & 1))*BB)*CC*96;
    for (int idx = tid; idx < TSL*16*96; idx += 704) {
      int tloc = idx / 1536, r = idx - tloc*1536, b = r / 96, dw = r - b*96;
      smem[(tloc*16 + b)*100 + dw] =
          hbs[((size_t)(bg*16 + b)*CC + tb + tloc)*96 + dw];
    }
  }
  __syncthreads();

  const int lane = tid & 63, wv = tid >> 6;
  const int quad = lane >> 4, n15 = lane & 15;
  // per-lane gx slab: (l*16 + bg*4 + quad), rows tb..
  uint16_t* gxo = gxs + (((size_t)(l*16 + bg*4 + quad)*CC + tb)*GG)*4;

  // ---- hoisted W_ih fragments + bias (static indices; regs) ----
  half8 wf[4][6];
  float bv[4] = {0.f, 0.f, 0.f, 0.f};
  #pragma unroll
  for (int ni = 0; ni < 4; ++ni) {
    int nt = wv + ni*11;
    if (nt < 41) {
      int wrow = nt*16 + n15;
      const half8* bsrc = (const half8*)(wihw + ((size_t)l*GG + wrow)*KPD);
      #pragma unroll
      for (int kk = 0; kk < 6; ++kk) wf[ni][kk] = bsrc[kk*4 + quad];
      bv[ni] = bp[wrow];
    }
  }

  for (int tloc = 0; tloc < tcnt; ++tloc) {
    const half8* asrc = (const half8*)(smem + tloc*1600); // batch stride 25 h8
    half8 af[6];
    #pragma unroll
    for (int kk = 0; kk < 6; ++kk) af[kk] = asrc[n15*25 + kk*4 + quad];
    #pragma unroll
    for (int ni = 0; ni < 4; ++ni) {
      int nt = wv + ni*11;
      if (nt < 41) {
        int wrow = nt*16 + n15;
        f32x4 a0 = {0.f,0.f,0.f,0.f};
        #pragma unroll
        for (int kk = 0; kk < 6; ++kk)
          a0 = __builtin_amdgcn_mfma_f32_16x16x32_f16(af[kk], wf[ni][kk], a0, 0, 0, 0);
        half2v p0; p0[0] = (_Float16)(a0[0] + bv[ni]); p0[1] = (_Float16)(a0[1] + bv[ni]);
        half2v p1; p1[0] = (_Float16)(a0[2] + bv[ni]); p1[1] = (_Float16)(a0[3] + bv[ni]);
        uint2 pk;
        pk.x = __builtin_bit_cast(uint32_t, p0);
        pk.y = __builtin_bit_cast(uint32_t, p1);
        *(uint2*)(gxo + ((size_t)tloc*GG + wrow)*4) = pk;
      }
    }
  }
}

// ---------------------------------------------------------------------------
// MFMA recurrence for one (l, 4-batch group, chunk). 704 thr (11 waves).
// m-duplication: only A/D rows 4q matter (D row m depends only on A row m;
// rows 4q+1..3 are never written after init and their D rows are discarded).
// Lane (n15, quad): all 4 gates of element e = wv*16+n15, batch gb = bg*4+quad.
// ---------------------------------------------------------------------------
__device__ __forceinline__ void rec_body(
    int l, int bg, int ch, const int* lengths,
    const uint32_t* whhw, const uint16_t* gxs, uint32_t* hring,
    float* state_c, uint32_t* state_h, uint32_t* smem, int tid) {

  const int gb0 = bg*4;
  int maxlen = 1;
  #pragma unroll
  for (int bi = 0; bi < 4; ++bi) {
    int L = lengths[gb0 + bi]; if (L < 1) L = 1; if (L > TT) L = TT;
    if (L > maxlen) maxlen = L;
  }
  const int t0 = ch*CC;
  if (t0 >= maxlen) return;                     // group fully frozen
  int t1 = t0 + CC; if (t1 > maxlen) t1 = maxlen;
  const int nst = t1 - t0;

  const int wv = tid >> 6, ln = tid & 63;
  const int quad = ln >> 4, n15 = ln & 15;
  const int e = wv*16 + n15;                    // 0..175
  const int evalid = (e < HH);
  const int gb = gb0 + quad;                    // this lane's batch

  int lenq = lengths[gb]; if (lenq < 1) lenq = 1; if (lenq > TT) lenq = TT;

  // resident W_hh fragments: 4 gates x 6 k-steps, half8 each (96 regs/AGPRs)
  half8 wB[24];
  {
    const half8* wb8 = (const half8*)(whhw + (size_t)l*GP*KPD);
    #pragma unroll
    for (int g = 0; g < 4; ++g) {
      int row = g*EP + e;
      #pragma unroll
      for (int kk = 0; kk < 6; ++kk)
        wB[g*6 + kk] = wb8[(size_t)row*24 + kk*4 + quad];
    }
  }

  float creg = 0.f;
  if (ch > 0 && evalid)
    creg = state_c[((size_t)l*BB + gb)*HH + e];

  // h double buffer in LDS: rows m=0..15, row m = batch gb0+(m>>2)
  uint32_t* hb0 = smem;
  uint32_t* hb1 = smem + 1600;
  for (int i2 = tid; i2 < 1600; i2 += 704) {
    int bb = i2 / 100, dd = i2 - bb*100;
    uint32_t v = 0;
    if (dd < 96 && ch > 0) v = state_h[((size_t)l*BB + gb0 + (bb >> 2))*96 + dd];
    hb0[i2] = v; hb1[i2] = v;
  }
  __syncthreads();

  // per-lane h bits for its (batch gb, element e)
  uint16_t hbit = ((const uint16_t*)hb0)[(quad*4)*200 + e];

  // single incrementing gx pointer; gate offsets are compile-time constants
  const uint16_t* gpt = gxs + (((size_t)(l*16 + bg)*CC)*GG)*4
                            + (size_t)e*4 + quad;
  uint16_t gxv[4];
  #pragma unroll
  for (int g = 0; g < 4; ++g) gxv[g] = gpt[g*(HH*4)];
  gpt += GG*4;

  // direct ring-publish pointer (u16), +192 halves per t
  const int dorb = (l < 2);
  uint16_t* rp;
  {
    uint16_t* hrb16 = (uint16_t*)(hring + ((size_t)(l*2 + (ch & 1))*BB)*CC*96);
    rp = hrb16 + ((size_t)gb*CC)*192 + e;
  }

  const int lo = n15*100 + quad*4;              // af lane offset (dwords)
  const int ho_off = (quad*4)*200 + e;          // hout u16 offset

  int p = 0;
  for (int it = 0; it < nst; ++it) {
    const int t = t0 + it;
    uint32_t* hin  = p ? hb1 : hb0;
    uint32_t* hout = p ? hb0 : hb1;

    // consume current gx (cvt only; added after the MFMA chain)
    float gxf0 = (float)__builtin_bit_cast(_Float16, gxv[0]);
    float gxf1 = (float)__builtin_bit_cast(_Float16, gxv[1]);
    float gxf2 = (float)__builtin_bit_cast(_Float16, gxv[2]);
    float gxf3 = (float)__builtin_bit_cast(_Float16, gxv[3]);
    // prefetch next row (last iter reads in-bounds junk, discarded)
    #pragma unroll
    for (int g = 0; g < 4; ++g) gxv[g] = gpt[g*(HH*4)];
    gpt += GG*4;

    // recurrent projection, C=0 on first MFMA (no splat init)
    f32x4 acc0, acc1, acc2, acc3;
    {
      const f32x4 z = {0.f, 0.f, 0.f, 0.f};
      half8 af = *(const half8*)&hin[lo];
      acc0 = __builtin_amdgcn_mfma_f32_16x16x32_f16(af, wB[0],  z, 0, 0, 0);
      acc1 = __builtin_amdgcn_mfma_f32_16x16x32_f16(af, wB[6],  z, 0, 0, 0);
      acc2 = __builtin_amdgcn_mfma_f32_16x16x32_f16(af, wB[12], z, 0, 0, 0);
      acc3 = __builtin_amdgcn_mfma_f32_16x16x32_f16(af, wB[18], z, 0, 0, 0);
    }
    #pragma unroll
    for (int kk = 1; kk < 6; ++kk) {
      half8 af = *(const half8*)&hin[lo + kk*16];
      acc0 = __builtin_amdgcn_mfma_f32_16x16x32_f16(af, wB[kk],      acc0, 0, 0, 0);
      acc1 = __builtin_amdgcn_mfma_f32_16x16x32_f16(af, wB[6 + kk],  acc1, 0, 0, 0);
      acc2 = __builtin_amdgcn_mfma_f32_16x16x32_f16(af, wB[12 + kk], acc2, 0, 0, 0);
      acc3 = __builtin_amdgcn_mfma_f32_16x16x32_f16(af, wB[18 + kk], acc3, 0, 0, 0);
    }
    // cell update: ONE slot per lane (D row quad*4)
    {
      float gi = acc0[0] + gxf0;
      float gf = acc1[0] + gxf1;
      float gg2 = acc2[0] + gxf2;
      float go = acc3[0] + gxf3;
      float cn = sigmf(gf)*creg + sigmf(gi)*tanhf_(gg2);
      float hv = sigmf(go)*tanhf_(cn);
      if (t < lenq) {                           // per-batch freeze
        creg = cn;
        _Float16 h16 = (_Float16)hv;
        hbit = __builtin_bit_cast(uint16_t, h16);
      }
      if (evalid) {
        ((uint16_t*)hout)[ho_off] = hbit;       // single write (row quad*4)
        if (dorb) *rp = hbit;                   // ring row it = h(t)
      }
      rp += 192;
    }
    // lgkm-only barrier: no vmcnt drain (ring stores / gx prefetch float)
    asm volatile("s_waitcnt lgkmcnt(0)" ::: "memory");
    __builtin_amdgcn_s_barrier();
    p ^= 1;
  }

  // persist state (ring already fully published per-step)
  uint32_t* hfin = p ? hb1 : hb0;
  uint32_t* shb = state_h + ((size_t)l*BB + gb0)*96;
  for (int i2 = tid; i2 < 4*96; i2 += 704) {
    int bb = i2 / 96, dd = i2 - bb*96;
    shb[(size_t)bb*96 + dd] = hfin[(bb*4)*100 + dd];
  }
  if (evalid)
    state_c[((size_t)l*BB + gb)*HH + e] = creg;
}

// ---------------------------------------------------------------------------
// fused step: blocks 0..191 = gemm(l, bg16, tslice, ch=j-2l),
//             blocks 192..239 = rec(l, bg4, ch=j-2l-1)
// ---------------------------------------------------------------------------
__global__ __launch_bounds__(704, 1) void kstep_f(
    int j, const int* lengths, const float* x,
    const uint32_t* wihw, const uint32_t* whhw,
    const float* b0, const float* b1, const float* b2,
    uint16_t* gx, uint32_t* hring, float* state_c, uint32_t* state_h) {
  __shared__ __align__(16) uint32_t smem[TSL*1600];     // 51.2 KB
  const int blk = blockIdx.x, tid = threadIdx.x;
  if (blk < 192) {
    const int l = blk >> 6, r = blk & 63, bg = r >> 4, ts = r & 15;
    const int ch = j - 2*l;
    if (ch < 0 || ch >= NCH) return;
    const float* bp = (l == 0) ? b0 : ((l == 1) ? b1 : b2);
    uint16_t* gxs = gx + (size_t)(ch & 1)*GX_SLOT_HALVES;
    gemm_body(l, bg, ts, ch, lengths, x, wihw, hring, bp, gxs, smem, tid);
  } else {
    const int idx = blk - 192;
    if (idx >= 48) return;
    const int l = idx >> 4, bg = idx & 15;
    const int ch = j - 2*l - 1;
    if (ch < 0 || ch >= NCH) return;
    const uint16_t* gxs = gx + (size_t)(ch & 1)*GX_SLOT_HALVES;
    rec_body(l, bg, ch, lengths, whhw, gxs, hring,
             state_c, state_h, smem, tid);
  }
}

// ---- sequential fallback (1 gx slot; gemm(i) then rec(i) each iteration) ----
__global__ __launch_bounds__(704, 1) void kgemm_s(
    int step, const int* lengths, const float* x,
    const uint32_t* wihw, const float* b0, const float* b1, const float* b2,
    uint16_t* gx, const uint32_t* hring) {
  __shared__ __align__(16) uint32_t smem[TSL*1600];
  const int blk = blockIdx.x;
  const int l = blk >> 6, r = blk & 63, bg = r >> 4, ts = r & 15;
  const int ch = step - l;
  if (ch < 0 || ch >= NCH) return;
  const float* bp = (l == 0) ? b0 : ((l == 1) ? b1 : b2);
  gemm_body(l, bg, ts, ch, lengths, x, wihw, hring, bp, gx, smem, threadIdx.x);
}

__global__ __launch_bounds__(704, 1) void krec_s(
    int step, const int* lengths,
    const uint32_t* whhw, const uint16_t* gx, uint32_t* hring,
    float* state_c, uint32_t* state_h) {
  __shared__ __align__(16) uint32_t smem[TSL*1600];
  const int idx = blockIdx.x;
  const int l = idx >> 4, bg = idx & 15;
  const int ch = step - l;
  if (ch < 0 || ch >= NCH) return;
  rec_body(l, bg, ch, lengths, whhw, gx, hring,
           state_c, state_h, smem, threadIdx.x);
}

// ---------------------------------------------------------------------------
// FC epilogue on layer-2 final hidden state
// ---------------------------------------------------------------------------
__global__ void kfc(const float* fcw, const float* fcb,
                    const uint32_t* state_h, float* out) {
  int b = blockIdx.x, o = threadIdx.x;
  if (o >= 7) return;
  const uint16_t* h16 = (const uint16_t*)(state_h + (size_t)(2*BB + b)*96);
  float s = fcb[o];
  for (int m = 0; m < HH; ++m) {
    _Float16 hv = __builtin_bit_cast(_Float16, h16[m]);
    s += fcw[o*HH + m] * (float)hv;
  }
  out[b*7 + o] = s;
}

// ---------------------------------------------------------------------------
extern "C" void kernel_launch(void* const* d_in, const int* in_sizes, int n_in,
                              void* d_out, int out_size, void* d_ws, size_t ws_size,
                              hipStream_t stream) {
  const float* x      = (const float*)d_in[0];
  const int*  lengths = (const int*)  d_in[1];
  const float* wih0   = (const float*)d_in[2];
  const float* whh0   = (const float*)d_in[3];
  const float* b0     = (const float*)d_in[4];
  const float* wih1   = (const float*)d_in[5];
  const float* whh1   = (const float*)d_in[6];
  const float* b1     = (const float*)d_in[7];
  const float* wih2   = (const float*)d_in[8];
  const float* whh2   = (const float*)d_in[9];
  const float* b2     = (const float*)d_in[10];
  const float* fcw    = (const float*)d_in[11];
  const float* fcb    = (const float*)d_in[12];

  const size_t off_wih = 0;
  const size_t off_whh = SZ_WIH;
  const size_t off_gx  = SZ_WIH + SZ_WHH;
  const size_t tail    = SZ_HR + SZ_SC + SZ_SH;
  const size_t need_fused = off_gx + 2*SZ_GX1 + tail;   // ~78.8 MB
  const size_t need_seq   = off_gx + 1*SZ_GX1 + tail;   // ~46.6 MB
  const int fused = (ws_size >= need_fused);
  if (!fused && ws_size < need_seq) return;             // loud, clean failure
  const size_t gx_bytes = fused ? 2*SZ_GX1 : SZ_GX1;
  const size_t off_hr = off_gx + gx_bytes;
  const size_t off_sc = off_hr + SZ_HR;
  const size_t off_sh = off_sc + SZ_SC;

  char* ws = (char*)d_ws;
  _Float16* wih16 = (_Float16*)(ws + off_wih);
  _Float16* whh16 = (_Float16*)(ws + off_whh);
  uint16_t* gxw   = (uint16_t*)(ws + off_gx);
  uint32_t* hrw   = (uint32_t*)(ws + off_hr);
  float*    scw   = (float*)   (ws + off_sc);
  uint32_t* shw   = (uint32_t*)(ws + off_sh);

  hipLaunchKernelGGL(kprep_w, dim3((3*GP*KPH + 255)/256), dim3(256), 0, stream,
                     wih0, whh0, wih1, whh1, wih2, whh2, wih16, whh16);
  hipLaunchKernelGGL(kzero, dim3((HR_DW + 255)/256), dim3(256), 0, stream,
                     hrw, HR_DW);

  if (fused) {
    for (int jj = 0; jj <= NCH + 4; ++jj) {             // j = 0..20
      hipLaunchKernelGGL(kstep_f, dim3(240), dim3(704), 0, stream,
                         jj, lengths, x, (const uint32_t*)wih16,
                         (const uint32_t*)whh16, b0, b1, b2,
                         gxw, hrw, scw, shw);
    }
  } else {
    for (int i = 0; i < NCH + 2; ++i) {
      hipLaunchKernelGGL(kgemm_s, dim3(192), dim3(704), 0, stream,
                         i, lengths, x, (const uint32_t*)wih16,
                         b0, b1, b2, gxw, (const uint32_t*)hrw);
      hipLaunchKernelGGL(krec_s, dim3(48), dim3(704), 0, stream,
                         i, lengths, (const uint32_t*)whh16,
                         (const uint16_t*)gxw, hrw, scw, shw);
    }
  }

  hipLaunchKernelGGL(kfc, dim3(64), dim3(64), 0, stream,
                     fcw, fcb, shw, (float*)d_out);
}